// Round 2
// baseline (591.263 us; speedup 1.0000x reference)
//
#include <hip/hip_runtime.h>
#include <math.h>

#define NTOK 4096
#define DIM 256
#define NHID 64
#define NHEADS 4
#define KSEL 6            // K+1
#define ALPHA_LR 0.2f
#define LNEPS 1e-5f
#define BIGN 768          // xm(256) | xr(256) | Wh(4*64)
#define JSPLIT 8
#define JCHUNK (NTOK / JSPLIT)   // 512

__device__ __forceinline__ float f4get(const float4& v, int k) {
    return (k == 0) ? v.x : (k == 1) ? v.y : (k == 2) ? v.z : v.w;
}

// sorted-ascending (lex (d,i)) top-6 insertion network; all indices static.
#define INSERT6(BD, BI, DV, JV)                                                   \
    if ((DV) < (BD)[5] || ((DV) == (BD)[5] && (JV) < (BI)[5])) {                  \
        bool l4 = ((DV) < (BD)[4]) || ((DV) == (BD)[4] && (JV) < (BI)[4]);        \
        bool l3 = ((DV) < (BD)[3]) || ((DV) == (BD)[3] && (JV) < (BI)[3]);        \
        bool l2 = ((DV) < (BD)[2]) || ((DV) == (BD)[2] && (JV) < (BI)[2]);        \
        bool l1 = ((DV) < (BD)[1]) || ((DV) == (BD)[1] && (JV) < (BI)[1]);        \
        bool l0 = ((DV) < (BD)[0]) || ((DV) == (BD)[0] && (JV) < (BI)[0]);        \
        (BD)[5] = l4 ? (BD)[4] : (DV);  (BI)[5] = l4 ? (BI)[4] : (JV);            \
        if (l4) { (BD)[4] = l3 ? (BD)[3] : (DV); (BI)[4] = l3 ? (BI)[3] : (JV); } \
        if (l3) { (BD)[3] = l2 ? (BD)[2] : (DV); (BI)[3] = l2 ? (BI)[2] : (JV); } \
        if (l2) { (BD)[2] = l1 ? (BD)[1] : (DV); (BI)[2] = l1 ? (BI)[1] : (JV); } \
        if (l1) { (BD)[1] = l0 ? (BD)[0] : (DV); (BI)[1] = l0 ? (BI)[0] : (JV); } \
        if (l0) { (BD)[0] = (DV);                (BI)[0] = (JV); }                \
    }

// ---------------- repack: BigB[256][768] = [Wm | Wr | W heads], BigBias[768] ----
__global__ void repack_kernel(const float* __restrict__ Wm, const float* __restrict__ bm,
                              const float* __restrict__ W,  const float* __restrict__ Wr,
                              const float* __restrict__ br,
                              float* __restrict__ BigB, float* __restrict__ BigBias) {
    int tid = blockIdx.x * blockDim.x + threadIdx.x;
    int total = DIM * BIGN;
    for (int e = tid; e < total; e += gridDim.x * blockDim.x) {
        int k = e / BIGN, col = e - k * BIGN;
        float v;
        if (col < 256)      v = Wm[k * 256 + col];
        else if (col < 512) v = Wr[k * 256 + (col - 256)];
        else {
            int c = col - 512;
            int h = c >> 6, d = c & 63;
            v = W[(h * DIM + k) * NHID + d];
        }
        BigB[e] = v;
    }
    if (tid < BIGN) {
        float b = 0.f;
        if (tid < 256)      b = bm[tid];
        else if (tid < 512) b = br[tid - 256];
        BigBias[tid] = b;
    }
}

// ---------------- GEMM: BigC[4096][768] = x[4096][256] @ BigB + BigBias --------
#define GEMM_SA 36
__global__ __launch_bounds__(256) void gemm_kernel(const float* __restrict__ A,
        const float* __restrict__ B, const float* __restrict__ bias,
        float* __restrict__ C) {
    __shared__ float As[64][GEMM_SA];   // [row][k]  (32 k used, pad to 36)
    __shared__ float Bs[32][64];        // [k][j]
    const int t  = threadIdx.x;
    const int tx = t & 15, ty = t >> 4;
    const int i0 = blockIdx.x * 64;
    const int j0 = blockIdx.y * 64;
    float c[4][4] = {};
    for (int kc = 0; kc < DIM / 32; ++kc) {
        __syncthreads();
        #pragma unroll
        for (int p = 0; p < 2; ++p) {
            int f  = t + p * 256;
            int ra = f >> 3, ka = (f & 7) * 4;
            *(float4*)&As[ra][ka] =
                *(const float4*)&A[(size_t)(i0 + ra) * DIM + kc * 32 + ka];
            int kb = f >> 4, jb = (f & 15) * 4;
            *(float4*)&Bs[kb][jb] =
                *(const float4*)&B[(size_t)(kc * 32 + kb) * BIGN + j0 + jb];
        }
        __syncthreads();
        #pragma unroll
        for (int kq = 0; kq < 8; ++kq) {
            float4 a4[4], b4[4];
            #pragma unroll
            for (int ii = 0; ii < 4; ++ii) a4[ii] = *(const float4*)&As[ty * 4 + ii][kq * 4];
            #pragma unroll
            for (int kk = 0; kk < 4; ++kk) b4[kk] = *(const float4*)&Bs[kq * 4 + kk][tx * 4];
            #pragma unroll
            for (int ii = 0; ii < 4; ++ii)
                #pragma unroll
                for (int kk = 0; kk < 4; ++kk)
                    #pragma unroll
                    for (int jj = 0; jj < 4; ++jj)
                        c[ii][jj] = fmaf(f4get(a4[ii], kk), f4get(b4[kk], jj), c[ii][jj]);
        }
    }
    #pragma unroll
    for (int ii = 0; ii < 4; ++ii) {
        int r = i0 + ty * 4 + ii;
        float4 bv = *(const float4*)&bias[j0 + tx * 4];
        float4 o;
        o.x = c[ii][0] + bv.x; o.y = c[ii][1] + bv.y;
        o.z = c[ii][2] + bv.z; o.w = c[ii][3] + bv.w;
        *(float4*)&C[(size_t)r * BIGN + j0 + tx * 4] = o;
    }
}

// ---------------- sq[n], e1[h][n], e2[h][n] ------------------------------------
__global__ __launch_bounds__(256) void sq_e_kernel(const float* __restrict__ BigC,
        const float* __restrict__ a, float* __restrict__ sq,
        float* __restrict__ e1, float* __restrict__ e2) {
    const int n = blockIdx.x;
    const int t = threadIdx.x;
    __shared__ float red[256];
    float xm = BigC[(size_t)n * BIGN + t];
    red[t] = xm * xm;
    __syncthreads();
    #pragma unroll
    for (int s = 128; s > 0; s >>= 1) { if (t < s) red[t] += red[t + s]; __syncthreads(); }
    if (t == 0) sq[n] = red[0];
    const int h = t >> 6, d = t & 63;
    float wh = BigC[(size_t)n * BIGN + 512 + t];
    float v1 = wh * a[h * 128 + d];
    float v2 = wh * a[h * 128 + 64 + d];
    #pragma unroll
    for (int s = 32; s > 0; s >>= 1) {
        v1 += __shfl_down(v1, s, 64);
        v2 += __shfl_down(v2, s, 64);
    }
    if (d == 0) { e1[h * NTOK + n] = v1; e2[h * NTOK + n] = v2; }
}

// ---------------- distance GEMM + fused per-thread register top-6 ---------------
// LDS: As/Bs [64][64], XOR-swizzled in 4-float chunks: chunk' = chunk ^ (row>>2).
// FMA-loop reads: a4 broadcast per 16-lane group; b4 chunk spread bijective -> free.
__global__ __launch_bounds__(256) void dist_topk_kernel(const float* __restrict__ BigC,
        const float* __restrict__ sq, float* __restrict__ candD, int* __restrict__ candI) {
    __shared__ float As[64][64];
    __shared__ float Bs[64][64];
    const int t  = threadIdx.x;
    const int tx = t & 15, ty = t >> 4;
    const int row0  = blockIdx.x * 64;
    const int jbase = blockIdx.y * JCHUNK;

    float bd[4][KSEL]; int bi[4][KSEL];
    #pragma unroll
    for (int ii = 0; ii < 4; ++ii)
        #pragma unroll
        for (int k = 0; k < KSEL; ++k) { bd[ii][k] = 3.0e38f; bi[ii][k] = 0x7fffffff; }

    for (int jt = 0; jt < JCHUNK / 64; ++jt) {
        const int j0 = jbase + jt * 64;
        float c[4][4] = {};
        float4 sq4 = *(const float4*)&sq[j0 + tx * 4];
        for (int kc = 0; kc < DIM / 64; ++kc) {
            __syncthreads();
            #pragma unroll
            for (int p = 0; p < 4; ++p) {
                int f = t + p * 256;
                int r = f >> 4, cc = f & 15;
                int sc = (cc ^ (r >> 2)) * 4;
                *(float4*)&As[r][sc] =
                    *(const float4*)&BigC[(size_t)(row0 + r) * BIGN + kc * 64 + cc * 4];
                *(float4*)&Bs[r][sc] =
                    *(const float4*)&BigC[(size_t)(j0 + r) * BIGN + kc * 64 + cc * 4];
            }
            __syncthreads();
            #pragma unroll
            for (int kq = 0; kq < 16; ++kq) {
                float4 a4[4], b4[4];
                #pragma unroll
                for (int ii = 0; ii < 4; ++ii)
                    a4[ii] = *(const float4*)&As[ty * 4 + ii][((kq ^ ty) & 15) * 4];
                #pragma unroll
                for (int jj = 0; jj < 4; ++jj)
                    b4[jj] = *(const float4*)&Bs[tx * 4 + jj][((kq ^ tx) & 15) * 4];
                #pragma unroll
                for (int ii = 0; ii < 4; ++ii)
                    #pragma unroll
                    for (int jj = 0; jj < 4; ++jj)
                        #pragma unroll
                        for (int kk = 0; kk < 4; ++kk)
                            c[ii][jj] = fmaf(f4get(a4[ii], kk), f4get(b4[jj], kk), c[ii][jj]);
            }
        }
        // key = sq_j - 2*dot  (sq_i is a row-constant shift: ordering-invariant)
        #pragma unroll
        for (int ii = 0; ii < 4; ++ii) {
            #pragma unroll
            for (int jj = 0; jj < 4; ++jj) {
                float dv = f4get(sq4, jj) - 2.0f * c[ii][jj];
                int   j  = j0 + tx * 4 + jj;
                INSERT6(bd[ii], bi[ii], dv, j);
            }
        }
    }

    // cross-tx merge: 2 passes of 32 rows via LDS overlay (stride 97 -> conflict-free)
    float* smD = &As[0][0];          // 32*97 = 3104 floats <= 4096
    int*   smI = (int*)&Bs[0][0];
    #pragma unroll
    for (int p = 0; p < 2; ++p) {
        __syncthreads();
        if ((ty >> 3) == p) {
            int lrb = (ty - p * 8) * 4;
            #pragma unroll
            for (int ii = 0; ii < 4; ++ii)
                #pragma unroll
                for (int k = 0; k < KSEL; ++k) {
                    smD[(lrb + ii) * 97 + tx * KSEL + k] = bd[ii][k];
                    smI[(lrb + ii) * 97 + tx * KSEL + k] = bi[ii][k];
                }
        }
        __syncthreads();
        if (t < 32) {
            int row = row0 + p * 32 + t;
            size_t obase = ((size_t)row * JSPLIT + blockIdx.y) * KSEL;
            float lastD = -3.0e38f; int lastI = -1;
            #pragma unroll 1
            for (int k = 0; k < KSEL; ++k) {
                float bdv = 3.4e38f; int biv = 0x7fffffff;
                #pragma unroll 4
                for (int q = 0; q < 96; ++q) {
                    float dv = smD[t * 97 + q]; int iv = smI[t * 97 + q];
                    bool after  = (dv > lastD) || (dv == lastD && iv > lastI);
                    bool better = (dv < bdv)  || (dv == bdv  && iv < biv);
                    if (after && better) { bdv = dv; biv = iv; }
                }
                candD[obase + k] = bdv; candI[obase + k] = biv;
                lastD = bdv; lastI = biv;
            }
        }
    }
}

// ---------------- merge per-range top-6 -> global top-6 ------------------------
__global__ void merge_kernel(const float* __restrict__ candD, const int* __restrict__ candI,
                             int* __restrict__ idx6) {
    int row = blockIdx.x * blockDim.x + threadIdx.x;
    if (row >= NTOK) return;
    size_t base = (size_t)row * JSPLIT * KSEL;
    float lastD = -3.0e38f; int lastI = -1;
    #pragma unroll 1
    for (int k = 0; k < KSEL; ++k) {
        float bdv = 3.4e38f; int biv = 0x7fffffff;
        #pragma unroll 1
        for (int q = 0; q < JSPLIT * KSEL; ++q) {
            float dv = candD[base + q]; int iv = candI[base + q];
            bool after  = (dv > lastD) || (dv == lastD && iv > lastI);
            bool better = (dv < bdv)  || (dv == bdv  && iv < biv);
            if (after && better) { bdv = dv; biv = iv; }
        }
        idx6[row * KSEL + k] = biv;
        lastD = bdv; lastI = biv;
    }
}

// ---------------- attention + residual + LN + ELU + out projection -------------
__global__ __launch_bounds__(256) void final_kernel(const float* __restrict__ BigC,
        const float* __restrict__ e1, const float* __restrict__ e2,
        const int* __restrict__ idx6, const float* __restrict__ ln_g,
        const float* __restrict__ ln_b, const float* __restrict__ Wo,
        const float* __restrict__ bo, float* __restrict__ out) {
    const int i = blockIdx.x;
    const int t = threadIdx.x;
    const int h = t >> 6;
    __shared__ int sidx[KSEL];
    __shared__ float red[256];
    if (t < KSEL) sidx[t] = idx6[i * KSEL + t];
    __syncthreads();
    const float e1i = e1[h * NTOK + i];
    float ev[KSEL];
    float m = -3.0e38f;
    #pragma unroll
    for (int k = 0; k < KSEL; ++k) {
        float v = e1i + e2[h * NTOK + sidx[k]];
        v = (v > 0.f) ? v : ALPHA_LR * v;
        ev[k] = v;
        m = fmaxf(m, v);
    }
    float ssum = 0.f;
    #pragma unroll
    for (int k = 0; k < KSEL; ++k) { ev[k] = expf(ev[k] - m); ssum += ev[k]; }
    float agg = 0.f;
    #pragma unroll
    for (int k = 0; k < KSEL; ++k)
        agg += ev[k] * BigC[(size_t)sidx[k] * BIGN + 512 + t];
    agg /= ssum;
    float hv = agg + BigC[(size_t)i * BIGN + 256 + t];
    // LayerNorm over 256
    red[t] = hv; __syncthreads();
    #pragma unroll
    for (int s = 128; s > 0; s >>= 1) { if (t < s) red[t] += red[t + s]; __syncthreads(); }
    float mu = red[0] * (1.f / 256.f);
    __syncthreads();
    float dv = hv - mu;
    red[t] = dv * dv; __syncthreads();
    #pragma unroll
    for (int s = 128; s > 0; s >>= 1) { if (t < s) red[t] += red[t + s]; __syncthreads(); }
    float var = red[0] * (1.f / 256.f);
    __syncthreads();
    float nv  = dv / sqrtf(var + LNEPS) * ln_g[t] + ln_b[t];
    float act = (nv > 0.f) ? nv : expm1f(nv);
    // out = act @ Wo + bo  (two 256-length dots)
    red[t] = act * Wo[t * 2 + 0]; __syncthreads();
    #pragma unroll
    for (int s = 128; s > 0; s >>= 1) { if (t < s) red[t] += red[t + s]; __syncthreads(); }
    float o0 = red[0];
    __syncthreads();
    red[t] = act * Wo[t * 2 + 1]; __syncthreads();
    #pragma unroll
    for (int s = 128; s > 0; s >>= 1) { if (t < s) red[t] += red[t + s]; __syncthreads(); }
    if (t == 0) { out[i * 2 + 0] = o0 + bo[0]; out[i * 2 + 1] = red[0] + bo[1]; }
}

extern "C" void kernel_launch(void* const* d_in, const int* in_sizes, int n_in,
                              void* d_out, int out_size, void* d_ws, size_t ws_size,
                              hipStream_t stream) {
    (void)in_sizes; (void)n_in; (void)out_size; (void)ws_size;
    const float* x    = (const float*)d_in[0];
    const float* Wm   = (const float*)d_in[1];
    const float* bm   = (const float*)d_in[2];
    const float* W    = (const float*)d_in[3];
    const float* a    = (const float*)d_in[4];
    const float* Wr   = (const float*)d_in[5];
    const float* br   = (const float*)d_in[6];
    const float* ln_g = (const float*)d_in[7];
    const float* ln_b = (const float*)d_in[8];
    const float* Wo   = (const float*)d_in[9];
    const float* bo   = (const float*)d_in[10];
    float* out = (float*)d_out;

    char* ws = (char*)d_ws;
    float* BigB    = (float*)(ws + 0);              // 256*768*4       = 786432
    float* BigBias = (float*)(ws + 786432);         // 768*4           -> 789504
    float* BigC    = (float*)(ws + 789504);         // 4096*768*4      -> 13372416
    float* sq      = (float*)(ws + 13372416);       // 4096*4          -> 13388800
    float* e1      = (float*)(ws + 13388800);       // 4*4096*4        -> 13454336
    float* e2      = (float*)(ws + 13454336);       // 4*4096*4        -> 13519872
    float* candD   = (float*)(ws + 13519872);       // 4096*48*4       -> 14306304
    int*   candI   = (int*)  (ws + 14306304);       // 4096*48*4       -> 15092736
    int*   idx6    = (int*)  (ws + 15092736);       // 4096*6*4        -> 15191040

    hipLaunchKernelGGL(repack_kernel, dim3(768), dim3(256), 0, stream,
                       Wm, bm, W, Wr, br, BigB, BigBias);
    hipLaunchKernelGGL(gemm_kernel, dim3(64, 12), dim3(256), 0, stream,
                       x, BigB, BigBias, BigC);
    hipLaunchKernelGGL(sq_e_kernel, dim3(4096), dim3(256), 0, stream,
                       BigC, a, sq, e1, e2);
    hipLaunchKernelGGL(dist_topk_kernel, dim3(64, JSPLIT), dim3(256), 0, stream,
                       BigC, sq, candD, candI);
    hipLaunchKernelGGL(merge_kernel, dim3(16), dim3(256), 0, stream,
                       candD, candI, idx6);
    hipLaunchKernelGGL(final_kernel, dim3(4096), dim3(256), 0, stream,
                       BigC, e1, e2, idx6, ln_g, ln_b, Wo, bo, out);
}

// Round 3
// 278.410 us; speedup vs baseline: 2.1237x; 2.1237x over previous
//
#include <hip/hip_runtime.h>
#include <math.h>

#define NTOK 4096
#define DIM 256
#define NHID 64
#define NHEADS 4
#define KSEL 6            // K+1
#define ALPHA_LR 0.2f
#define LNEPS 1e-5f
#define BIGN 768          // xm(256) | xr(256) | Wh(4*64)
#define JSPLIT 16
#define JCHUNK (NTOK / JSPLIT)   // 256

typedef __attribute__((ext_vector_type(4))) float f32x4;
typedef __attribute__((ext_vector_type(8))) short short8;
typedef __attribute__((ext_vector_type(8))) unsigned short us8;

__device__ __forceinline__ float f4get(const float4& v, int k) {
    return (k == 0) ? v.x : (k == 1) ? v.y : (k == 2) ? v.z : v.w;
}

__device__ __forceinline__ void gload16(const void* g, void* l) {
    __builtin_amdgcn_global_load_lds(
        (const __attribute__((address_space(1))) void*)g,
        (__attribute__((address_space(3))) void*)l, 16, 0, 0);
}

// sorted-ascending (lex (d,i)) top-6 insertion network; all indices static.
#define INSERT6(BD, BI, DV, JV)                                                   \
    if ((DV) < (BD)[5] || ((DV) == (BD)[5] && (JV) < (BI)[5])) {                  \
        bool l4 = ((DV) < (BD)[4]) || ((DV) == (BD)[4] && (JV) < (BI)[4]);        \
        bool l3 = ((DV) < (BD)[3]) || ((DV) == (BD)[3] && (JV) < (BI)[3]);        \
        bool l2 = ((DV) < (BD)[2]) || ((DV) == (BD)[2] && (JV) < (BI)[2]);        \
        bool l1 = ((DV) < (BD)[1]) || ((DV) == (BD)[1] && (JV) < (BI)[1]);        \
        bool l0 = ((DV) < (BD)[0]) || ((DV) == (BD)[0] && (JV) < (BI)[0]);        \
        (BD)[5] = l4 ? (BD)[4] : (DV);  (BI)[5] = l4 ? (BI)[4] : (JV);            \
        if (l4) { (BD)[4] = l3 ? (BD)[3] : (DV); (BI)[4] = l3 ? (BI)[3] : (JV); } \
        if (l3) { (BD)[3] = l2 ? (BD)[2] : (DV); (BI)[3] = l2 ? (BI)[2] : (JV); } \
        if (l2) { (BD)[2] = l1 ? (BD)[1] : (DV); (BI)[2] = l1 ? (BI)[1] : (JV); } \
        if (l1) { (BD)[1] = l0 ? (BD)[0] : (DV); (BI)[1] = l0 ? (BI)[0] : (JV); } \
        if (l0) { (BD)[0] = (DV);                (BI)[0] = (JV); }                \
    }

// ---------------- repack: BigB[256][768] = [Wm | Wr | W heads], BigBias[768] ----
__global__ void repack_kernel(const float* __restrict__ Wm, const float* __restrict__ bm,
                              const float* __restrict__ W,  const float* __restrict__ Wr,
                              const float* __restrict__ br,
                              float* __restrict__ BigB, float* __restrict__ BigBias) {
    int tid = blockIdx.x * blockDim.x + threadIdx.x;
    int total = DIM * BIGN;
    for (int e = tid; e < total; e += gridDim.x * blockDim.x) {
        int k = e / BIGN, col = e - k * BIGN;
        float v;
        if (col < 256)      v = Wm[k * 256 + col];
        else if (col < 512) v = Wr[k * 256 + (col - 256)];
        else {
            int c = col - 512;
            int h = c >> 6, d = c & 63;
            v = W[(h * DIM + k) * NHID + d];
        }
        BigB[e] = v;
    }
    if (tid < BIGN) {
        float b = 0.f;
        if (tid < 256)      b = bm[tid];
        else if (tid < 512) b = br[tid - 256];
        BigBias[tid] = b;
    }
}

// ---------------- GEMM: BigC[4096][768] = x[4096][256] @ BigB + BigBias --------
#define GEMM_SA 36
__global__ __launch_bounds__(256) void gemm_kernel(const float* __restrict__ A,
        const float* __restrict__ B, const float* __restrict__ bias,
        float* __restrict__ C) {
    __shared__ float As[64][GEMM_SA];   // [row][k]  (32 k used, pad to 36)
    __shared__ float Bs[32][64];        // [k][j]
    const int t  = threadIdx.x;
    const int tx = t & 15, ty = t >> 4;
    const int i0 = blockIdx.x * 64;
    const int j0 = blockIdx.y * 64;
    float c[4][4] = {};
    for (int kc = 0; kc < DIM / 32; ++kc) {
        __syncthreads();
        #pragma unroll
        for (int p = 0; p < 2; ++p) {
            int f  = t + p * 256;
            int ra = f >> 3, ka = (f & 7) * 4;
            *(float4*)&As[ra][ka] =
                *(const float4*)&A[(size_t)(i0 + ra) * DIM + kc * 32 + ka];
            int kb = f >> 4, jb = (f & 15) * 4;
            *(float4*)&Bs[kb][jb] =
                *(const float4*)&B[(size_t)(kc * 32 + kb) * BIGN + j0 + jb];
        }
        __syncthreads();
        #pragma unroll
        for (int kq = 0; kq < 8; ++kq) {
            float4 a4[4], b4[4];
            #pragma unroll
            for (int ii = 0; ii < 4; ++ii) a4[ii] = *(const float4*)&As[ty * 4 + ii][kq * 4];
            #pragma unroll
            for (int kk = 0; kk < 4; ++kk) b4[kk] = *(const float4*)&Bs[kq * 4 + kk][tx * 4];
            #pragma unroll
            for (int ii = 0; ii < 4; ++ii)
                #pragma unroll
                for (int kk = 0; kk < 4; ++kk)
                    #pragma unroll
                    for (int jj = 0; jj < 4; ++jj)
                        c[ii][jj] = fmaf(f4get(a4[ii], kk), f4get(b4[kk], jj), c[ii][jj]);
        }
    }
    #pragma unroll
    for (int ii = 0; ii < 4; ++ii) {
        int r = i0 + ty * 4 + ii;
        float4 bv = *(const float4*)&bias[j0 + tx * 4];
        float4 o;
        o.x = c[ii][0] + bv.x; o.y = c[ii][1] + bv.y;
        o.z = c[ii][2] + bv.z; o.w = c[ii][3] + bv.w;
        *(float4*)&C[(size_t)r * BIGN + j0 + tx * 4] = o;
    }
}

// ---------------- convert xm (BigC cols 0..255) -> bf16 hi/lo planes -----------
__global__ __launch_bounds__(256) void convert_kernel(const float* __restrict__ BigC,
        unsigned short* __restrict__ xmh, unsigned short* __restrict__ xml) {
    int id = blockIdx.x * 256 + threadIdx.x;      // 131072 threads
    int row = id >> 5, c8 = (id & 31) * 8;
    const float* p = &BigC[(size_t)row * BIGN + c8];
    float4 v0 = *(const float4*)p;
    float4 v1 = *(const float4*)(p + 4);
    float vv[8] = {v0.x, v0.y, v0.z, v0.w, v1.x, v1.y, v1.z, v1.w};
    us8 hh, ll;
    #pragma unroll
    for (int r = 0; r < 8; ++r) {
        unsigned int u = __float_as_uint(vv[r]);
        unsigned int hb = (u + 0x7fffu + ((u >> 16) & 1u)) >> 16;
        float hf = __uint_as_float(hb << 16);
        float lof = vv[r] - hf;
        unsigned int u2 = __float_as_uint(lof);
        unsigned int lb = (u2 + 0x7fffu + ((u2 >> 16) & 1u)) >> 16;
        hh[r] = (unsigned short)hb;
        ll[r] = (unsigned short)lb;
    }
    *(us8*)&xmh[(size_t)row * DIM + c8] = hh;
    *(us8*)&xml[(size_t)row * DIM + c8] = ll;
}

// ---------------- sq[n], e1[h][n], e2[h][n] ------------------------------------
__global__ __launch_bounds__(256) void sq_e_kernel(const float* __restrict__ BigC,
        const float* __restrict__ a, float* __restrict__ sq,
        float* __restrict__ e1, float* __restrict__ e2) {
    const int n = blockIdx.x;
    const int t = threadIdx.x;
    __shared__ float red[256];
    float xm = BigC[(size_t)n * BIGN + t];
    red[t] = xm * xm;
    __syncthreads();
    #pragma unroll
    for (int s = 128; s > 0; s >>= 1) { if (t < s) red[t] += red[t + s]; __syncthreads(); }
    if (t == 0) sq[n] = red[0];
    const int h = t >> 6, d = t & 63;
    float wh = BigC[(size_t)n * BIGN + 512 + t];
    float v1 = wh * a[h * 128 + d];
    float v2 = wh * a[h * 128 + 64 + d];
    #pragma unroll
    for (int s = 32; s > 0; s >>= 1) {
        v1 += __shfl_down(v1, s, 64);
        v2 += __shfl_down(v2, s, 64);
    }
    if (d == 0) { e1[h * NTOK + n] = v1; e2[h * NTOK + n] = v2; }
}

// ---------------- distance via bf16x3 MFMA + fused top-6 -----------------------
// Block: 256 thr (4 waves), tile 64i x 128j, K-chunks of 64, JCHUNK=256 (2 jt).
// LDS: Ah/Al [64][64] bf16, Bh/Bl [128][64] bf16 = 48KB, chunk-XOR swizzled
// (16B chunk c stored at c ^ (row&7)); staged via global_load_lds w/ pre-swizzled
// global source (linear LDS dest).  dot = hi*hi + hi*lo + lo*hi in fp32 MFMA.
__global__ __launch_bounds__(256) void dist_topk_kernel(
        const unsigned short* __restrict__ xmh, const unsigned short* __restrict__ xml,
        const float* __restrict__ sq, float* __restrict__ candD, int* __restrict__ candI) {
    __shared__ __align__(16) unsigned short sh[24576];   // 48KB
    unsigned short* Ah = sh;            // [64][64]
    unsigned short* Al = sh + 4096;
    unsigned short* Bh = sh + 8192;     // [128][64]
    unsigned short* Bl = sh + 16384;

    const int t = threadIdx.x;
    const int l = t & 63;
    const int w = t >> 6;               // wave 0..3
    const int wi = w >> 1;              // i-half (32 rows)
    const int wj = w & 1;               // j-half (64 cols)
    const int i0 = blockIdx.x * 64;
    const int jbase = blockIdx.y * JCHUNK;
    const int csrc = (l & 7) ^ ((l >> 3) & 7);   // pre-swizzled source chunk
    const int lrow8 = l >> 3;                    // row within 8-row slot

    float bd[KSEL]; int bi[KSEL];
    #pragma unroll
    for (int k = 0; k < KSEL; ++k) { bd[k] = 3.0e38f; bi[k] = 0x7fffffff; }

    for (int jt = 0; jt < JCHUNK / 128; ++jt) {
        const int j0 = jbase + jt * 128;
        f32x4 acc[2][4] = {};

        for (int kc = 0; kc < 4; ++kc) {
            __syncthreads();
            // ---- stage: A planes (2 slots/wave), B planes (4 slots/wave) ----
            #pragma unroll
            for (int q = 0; q < 2; ++q) {
                int r0 = (w * 2 + q) * 8;
                size_t goff = (size_t)(i0 + r0 + lrow8) * DIM + kc * 64 + csrc * 8;
                gload16(xmh + goff, &Ah[r0 * 64]);
                gload16(xml + goff, &Al[r0 * 64]);
            }
            #pragma unroll
            for (int q = 0; q < 4; ++q) {
                int r0 = (w * 4 + q) * 8;
                size_t goff = (size_t)(j0 + r0 + lrow8) * DIM + kc * 64 + csrc * 8;
                gload16(xmh + goff, &Bh[r0 * 64]);
                gload16(xml + goff, &Bl[r0 * 64]);
            }
            asm volatile("s_waitcnt vmcnt(0)" ::: "memory");
            __syncthreads();
            // ---- compute ----
            #pragma unroll
            for (int ksub = 0; ksub < 2; ++ksub) {
                const int cc = ((ksub * 4 + (l >> 4)) ^ (l & 7)) * 8;
                short8 ah[2], al[2], bh[4], bl[4];
                #pragma unroll
                for (int ti = 0; ti < 2; ++ti) {
                    int r = wi * 32 + ti * 16 + (l & 15);
                    ah[ti] = *(const short8*)&Ah[r * 64 + cc];
                    al[ti] = *(const short8*)&Al[r * 64 + cc];
                }
                #pragma unroll
                for (int tj = 0; tj < 4; ++tj) {
                    int r = wj * 64 + tj * 16 + (l & 15);
                    bh[tj] = *(const short8*)&Bh[r * 64 + cc];
                    bl[tj] = *(const short8*)&Bl[r * 64 + cc];
                }
                #pragma unroll
                for (int ti = 0; ti < 2; ++ti)
                    #pragma unroll
                    for (int tj = 0; tj < 4; ++tj) {
                        acc[ti][tj] = __builtin_amdgcn_mfma_f32_16x16x32_bf16(
                            ah[ti], bh[tj], acc[ti][tj], 0, 0, 0);
                        acc[ti][tj] = __builtin_amdgcn_mfma_f32_16x16x32_bf16(
                            ah[ti], bl[tj], acc[ti][tj], 0, 0, 0);
                        acc[ti][tj] = __builtin_amdgcn_mfma_f32_16x16x32_bf16(
                            al[ti], bh[tj], acc[ti][tj], 0, 0, 0);
                    }
            }
        }

        // ---- dump dot-products to LDS (overlay), keys scanned per-thread ----
        __syncthreads();
        float* Kd = (float*)sh;                         // [64][132]
        #pragma unroll
        for (int ti = 0; ti < 2; ++ti) {
            int ib = wi * 32 + ti * 16 + ((l >> 4) << 2);
            #pragma unroll
            for (int tj = 0; tj < 4; ++tj) {
                int jb = wj * 64 + tj * 16 + (l & 15);
                #pragma unroll
                for (int r = 0; r < 4; ++r)
                    Kd[(ib + r) * 132 + jb] = acc[ti][tj][r];
            }
        }
        __syncthreads();
        // scan: thread t -> row t>>2, 32-j slice (t&3)*32
        {
            const int il = t >> 2;
            const int jl0 = (t & 3) * 32;
            #pragma unroll
            for (int q4 = 0; q4 < 8; ++q4) {
                float4 dv = *(const float4*)&Kd[il * 132 + jl0 + q4 * 4];
                float4 sv = *(const float4*)&sq[j0 + jl0 + q4 * 4];
                #pragma unroll
                for (int r = 0; r < 4; ++r) {
                    float key = f4get(sv, r) - 2.0f * f4get(dv, r);
                    int   j   = j0 + jl0 + q4 * 4 + r;
                    INSERT6(bd, bi, key, j);
                }
            }
        }
    }

    // ---- block-level merge: 4 threads/row -> row top-6 -> candD/candI --------
    __syncthreads();
    float* MD = (float*)sh;                 // [64][24]
    int*   MI = (int*)sh + 64 * 24;
    {
        int base = (t >> 2) * 24 + (t & 3) * 6;
        #pragma unroll
        for (int k = 0; k < KSEL; ++k) { MD[base + k] = bd[k]; MI[base + k] = bi[k]; }
    }
    __syncthreads();
    if (t < 64) {
        size_t obase = ((size_t)(i0 + t) * JSPLIT + blockIdx.y) * KSEL;
        float lastD = -3.0e38f; int lastI = -1;
        #pragma unroll 1
        for (int k = 0; k < KSEL; ++k) {
            float bdv = 3.4e38f; int biv = 0x7fffffff;
            #pragma unroll 4
            for (int q = 0; q < 24; ++q) {
                float dv = MD[t * 24 + q]; int iv = MI[t * 24 + q];
                bool after  = (dv > lastD) || (dv == lastD && iv > lastI);
                bool better = (dv < bdv)  || (dv == bdv  && iv < biv);
                if (after && better) { bdv = dv; biv = iv; }
            }
            candD[obase + k] = bdv; candI[obase + k] = biv;
            lastD = bdv; lastI = biv;
        }
    }
}

// ---------------- merge per-range top-6 -> global top-6 ------------------------
__global__ void merge_kernel(const float* __restrict__ candD, const int* __restrict__ candI,
                             int* __restrict__ idx6) {
    int row = blockIdx.x * blockDim.x + threadIdx.x;
    if (row >= NTOK) return;
    size_t base = (size_t)row * JSPLIT * KSEL;
    float lastD = -3.0e38f; int lastI = -1;
    #pragma unroll 1
    for (int k = 0; k < KSEL; ++k) {
        float bdv = 3.4e38f; int biv = 0x7fffffff;
        #pragma unroll 1
        for (int q = 0; q < JSPLIT * KSEL; ++q) {
            float dv = candD[base + q]; int iv = candI[base + q];
            bool after  = (dv > lastD) || (dv == lastD && iv > lastI);
            bool better = (dv < bdv)  || (dv == bdv  && iv < biv);
            if (after && better) { bdv = dv; biv = iv; }
        }
        idx6[row * KSEL + k] = biv;
        lastD = bdv; lastI = biv;
    }
}

// ---------------- attention + residual + LN + ELU + out projection -------------
__global__ __launch_bounds__(256) void final_kernel(const float* __restrict__ BigC,
        const float* __restrict__ e1, const float* __restrict__ e2,
        const int* __restrict__ idx6, const float* __restrict__ ln_g,
        const float* __restrict__ ln_b, const float* __restrict__ Wo,
        const float* __restrict__ bo, float* __restrict__ out) {
    const int i = blockIdx.x;
    const int t = threadIdx.x;
    const int h = t >> 6;
    __shared__ int sidx[KSEL];
    __shared__ float red[256];
    if (t < KSEL) sidx[t] = idx6[i * KSEL + t];
    __syncthreads();
    const float e1i = e1[h * NTOK + i];
    float ev[KSEL];
    float m = -3.0e38f;
    #pragma unroll
    for (int k = 0; k < KSEL; ++k) {
        float v = e1i + e2[h * NTOK + sidx[k]];
        v = (v > 0.f) ? v : ALPHA_LR * v;
        ev[k] = v;
        m = fmaxf(m, v);
    }
    float ssum = 0.f;
    #pragma unroll
    for (int k = 0; k < KSEL; ++k) { ev[k] = expf(ev[k] - m); ssum += ev[k]; }
    float agg = 0.f;
    #pragma unroll
    for (int k = 0; k < KSEL; ++k)
        agg += ev[k] * BigC[(size_t)sidx[k] * BIGN + 512 + t];
    agg /= ssum;
    float hv = agg + BigC[(size_t)i * BIGN + 256 + t];
    // LayerNorm over 256
    red[t] = hv; __syncthreads();
    #pragma unroll
    for (int s = 128; s > 0; s >>= 1) { if (t < s) red[t] += red[t + s]; __syncthreads(); }
    float mu = red[0] * (1.f / 256.f);
    __syncthreads();
    float dv = hv - mu;
    red[t] = dv * dv; __syncthreads();
    #pragma unroll
    for (int s = 128; s > 0; s >>= 1) { if (t < s) red[t] += red[t + s]; __syncthreads(); }
    float var = red[0] * (1.f / 256.f);
    __syncthreads();
    float nv  = dv / sqrtf(var + LNEPS) * ln_g[t] + ln_b[t];
    float act = (nv > 0.f) ? nv : expm1f(nv);
    // out = act @ Wo + bo  (two 256-length dots)
    red[t] = act * Wo[t * 2 + 0]; __syncthreads();
    #pragma unroll
    for (int s = 128; s > 0; s >>= 1) { if (t < s) red[t] += red[t + s]; __syncthreads(); }
    float o0 = red[0];
    __syncthreads();
    red[t] = act * Wo[t * 2 + 1]; __syncthreads();
    #pragma unroll
    for (int s = 128; s > 0; s >>= 1) { if (t < s) red[t] += red[t + s]; __syncthreads(); }
    if (t == 0) { out[i * 2 + 0] = o0 + bo[0]; out[i * 2 + 1] = red[0] + bo[1]; }
}

extern "C" void kernel_launch(void* const* d_in, const int* in_sizes, int n_in,
                              void* d_out, int out_size, void* d_ws, size_t ws_size,
                              hipStream_t stream) {
    (void)in_sizes; (void)n_in; (void)out_size; (void)ws_size;
    const float* x    = (const float*)d_in[0];
    const float* Wm   = (const float*)d_in[1];
    const float* bm   = (const float*)d_in[2];
    const float* W    = (const float*)d_in[3];
    const float* a    = (const float*)d_in[4];
    const float* Wr   = (const float*)d_in[5];
    const float* br   = (const float*)d_in[6];
    const float* ln_g = (const float*)d_in[7];
    const float* ln_b = (const float*)d_in[8];
    const float* Wo   = (const float*)d_in[9];
    const float* bo   = (const float*)d_in[10];
    float* out = (float*)d_out;

    char* ws = (char*)d_ws;
    float*          BigB    = (float*)(ws + 0);              // 786432 B
    float*          BigBias = (float*)(ws + 786432);         // -> 789504
    float*          BigC    = (float*)(ws + 789504);         // -> 13372416
    float*          sq      = (float*)(ws + 13372416);       // -> 13388800
    float*          e1      = (float*)(ws + 13388800);       // -> 13454336
    float*          e2      = (float*)(ws + 13454336);       // -> 13519872
    unsigned short* xmh     = (unsigned short*)(ws + 13519872); // -> 15617024
    unsigned short* xml     = (unsigned short*)(ws + 15617024); // -> 17714176
    float*          candD   = (float*)(ws + 17714176);       // 4096*16*6*4 -> 19287040
    int*            candI   = (int*)  (ws + 19287040);       // -> 20859904
    int*            idx6    = (int*)  (ws + 20859904);       // -> 20958208

    hipLaunchKernelGGL(repack_kernel, dim3(768), dim3(256), 0, stream,
                       Wm, bm, W, Wr, br, BigB, BigBias);
    hipLaunchKernelGGL(gemm_kernel, dim3(64, 12), dim3(256), 0, stream,
                       x, BigB, BigBias, BigC);
    hipLaunchKernelGGL(convert_kernel, dim3(512), dim3(256), 0, stream,
                       BigC, xmh, xml);
    hipLaunchKernelGGL(sq_e_kernel, dim3(4096), dim3(256), 0, stream,
                       BigC, a, sq, e1, e2);
    hipLaunchKernelGGL(dist_topk_kernel, dim3(64, JSPLIT), dim3(256), 0, stream,
                       xmh, xml, sq, candD, candI);
    hipLaunchKernelGGL(merge_kernel, dim3(16), dim3(256), 0, stream,
                       candD, candI, idx6);
    hipLaunchKernelGGL(final_kernel, dim3(4096), dim3(256), 0, stream,
                       BigC, e1, e2, idx6, ln_g, ln_b, Wo, bo, out);
}

// Round 4
// 155.087 us; speedup vs baseline: 3.8125x; 1.7952x over previous
//
#include <hip/hip_runtime.h>
#include <math.h>

#define NTOK 4096
#define DIM 256
#define NHID 64
#define NHEADS 4
#define KSEL 6            // K+1
#define ALPHA_LR 0.2f
#define LNEPS 1e-5f
#define BIGN 768          // xm(256) | xr(256) | Wh(4*64)
#define JSPLIT 16
#define JCHUNK (NTOK / JSPLIT)   // 256

typedef __attribute__((ext_vector_type(4))) float f32x4;
typedef __attribute__((ext_vector_type(8))) short short8;
typedef __attribute__((ext_vector_type(8))) unsigned short us8;

__device__ __forceinline__ float f4get(const float4& v, int k) {
    return (k == 0) ? v.x : (k == 1) ? v.y : (k == 2) ? v.z : v.w;
}

__device__ __forceinline__ void gload16(const void* g, void* l) {
    __builtin_amdgcn_global_load_lds(
        (const __attribute__((address_space(1))) void*)g,
        (__attribute__((address_space(3))) void*)l, 16, 0, 0);
}

// sorted-ascending (lex (d,i)) top-6 insertion network; all indices static.
#define INSERT6(BD, BI, DV, JV)                                                   \
    if ((DV) < (BD)[5] || ((DV) == (BD)[5] && (JV) < (BI)[5])) {                  \
        bool l4 = ((DV) < (BD)[4]) || ((DV) == (BD)[4] && (JV) < (BI)[4]);        \
        bool l3 = ((DV) < (BD)[3]) || ((DV) == (BD)[3] && (JV) < (BI)[3]);        \
        bool l2 = ((DV) < (BD)[2]) || ((DV) == (BD)[2] && (JV) < (BI)[2]);        \
        bool l1 = ((DV) < (BD)[1]) || ((DV) == (BD)[1] && (JV) < (BI)[1]);        \
        bool l0 = ((DV) < (BD)[0]) || ((DV) == (BD)[0] && (JV) < (BI)[0]);        \
        (BD)[5] = l4 ? (BD)[4] : (DV);  (BI)[5] = l4 ? (BI)[4] : (JV);            \
        if (l4) { (BD)[4] = l3 ? (BD)[3] : (DV); (BI)[4] = l3 ? (BI)[3] : (JV); } \
        if (l3) { (BD)[3] = l2 ? (BD)[2] : (DV); (BI)[3] = l2 ? (BI)[2] : (JV); } \
        if (l2) { (BD)[2] = l1 ? (BD)[1] : (DV); (BI)[2] = l1 ? (BI)[1] : (JV); } \
        if (l1) { (BD)[1] = l0 ? (BD)[0] : (DV); (BI)[1] = l0 ? (BI)[0] : (JV); } \
        if (l0) { (BD)[0] = (DV);                (BI)[0] = (JV); }                \
    }

// ---------------- repack: BigB[256][768] = [Wm | Wr | W heads], BigBias[768] ----
__global__ void repack_kernel(const float* __restrict__ Wm, const float* __restrict__ bm,
                              const float* __restrict__ W,  const float* __restrict__ Wr,
                              const float* __restrict__ br,
                              float* __restrict__ BigB, float* __restrict__ BigBias) {
    int tid = blockIdx.x * blockDim.x + threadIdx.x;
    int total = DIM * BIGN;
    for (int e = tid; e < total; e += gridDim.x * blockDim.x) {
        int k = e / BIGN, col = e - k * BIGN;
        float v;
        if (col < 256)      v = Wm[k * 256 + col];
        else if (col < 512) v = Wr[k * 256 + (col - 256)];
        else {
            int c = col - 512;
            int h = c >> 6, d = c & 63;
            v = W[(h * DIM + k) * NHID + d];
        }
        BigB[e] = v;
    }
    if (tid < BIGN) {
        float b = 0.f;
        if (tid < 256)      b = bm[tid];
        else if (tid < 512) b = br[tid - 256];
        BigBias[tid] = b;
    }
}

// ---------------- GEMM: BigC[4096][768] = x[4096][256] @ BigB + BigBias --------
#define GEMM_SA 36
__global__ __launch_bounds__(256) void gemm_kernel(const float* __restrict__ A,
        const float* __restrict__ B, const float* __restrict__ bias,
        float* __restrict__ C) {
    __shared__ float As[64][GEMM_SA];   // [row][k]  (32 k used, pad to 36)
    __shared__ float Bs[32][64];        // [k][j]
    const int t  = threadIdx.x;
    const int tx = t & 15, ty = t >> 4;
    const int i0 = blockIdx.x * 64;
    const int j0 = blockIdx.y * 64;
    float c[4][4] = {};
    for (int kc = 0; kc < DIM / 32; ++kc) {
        __syncthreads();
        #pragma unroll
        for (int p = 0; p < 2; ++p) {
            int f  = t + p * 256;
            int ra = f >> 3, ka = (f & 7) * 4;
            *(float4*)&As[ra][ka] =
                *(const float4*)&A[(size_t)(i0 + ra) * DIM + kc * 32 + ka];
            int kb = f >> 4, jb = (f & 15) * 4;
            *(float4*)&Bs[kb][jb] =
                *(const float4*)&B[(size_t)(kc * 32 + kb) * BIGN + j0 + jb];
        }
        __syncthreads();
        #pragma unroll
        for (int kq = 0; kq < 8; ++kq) {
            float4 a4[4], b4[4];
            #pragma unroll
            for (int ii = 0; ii < 4; ++ii) a4[ii] = *(const float4*)&As[ty * 4 + ii][kq * 4];
            #pragma unroll
            for (int kk = 0; kk < 4; ++kk) b4[kk] = *(const float4*)&Bs[kq * 4 + kk][tx * 4];
            #pragma unroll
            for (int ii = 0; ii < 4; ++ii)
                #pragma unroll
                for (int kk = 0; kk < 4; ++kk)
                    #pragma unroll
                    for (int jj = 0; jj < 4; ++jj)
                        c[ii][jj] = fmaf(f4get(a4[ii], kk), f4get(b4[kk], jj), c[ii][jj]);
        }
    }
    #pragma unroll
    for (int ii = 0; ii < 4; ++ii) {
        int r = i0 + ty * 4 + ii;
        float4 bv = *(const float4*)&bias[j0 + tx * 4];
        float4 o;
        o.x = c[ii][0] + bv.x; o.y = c[ii][1] + bv.y;
        o.z = c[ii][2] + bv.z; o.w = c[ii][3] + bv.w;
        *(float4*)&C[(size_t)r * BIGN + j0 + tx * 4] = o;
    }
}

// ---------------- convert xm (BigC cols 0..255) -> bf16 hi/lo planes -----------
__global__ __launch_bounds__(256) void convert_kernel(const float* __restrict__ BigC,
        unsigned short* __restrict__ xmh, unsigned short* __restrict__ xml) {
    int id = blockIdx.x * 256 + threadIdx.x;      // 131072 threads
    int row = id >> 5, c8 = (id & 31) * 8;
    const float* p = &BigC[(size_t)row * BIGN + c8];
    float4 v0 = *(const float4*)p;
    float4 v1 = *(const float4*)(p + 4);
    float vv[8] = {v0.x, v0.y, v0.z, v0.w, v1.x, v1.y, v1.z, v1.w};
    us8 hh, ll;
    #pragma unroll
    for (int r = 0; r < 8; ++r) {
        unsigned int u = __float_as_uint(vv[r]);
        unsigned int hb = (u + 0x7fffu + ((u >> 16) & 1u)) >> 16;
        float hf = __uint_as_float(hb << 16);
        float lof = vv[r] - hf;
        unsigned int u2 = __float_as_uint(lof);
        unsigned int lb = (u2 + 0x7fffu + ((u2 >> 16) & 1u)) >> 16;
        hh[r] = (unsigned short)hb;
        ll[r] = (unsigned short)lb;
    }
    *(us8*)&xmh[(size_t)row * DIM + c8] = hh;
    *(us8*)&xml[(size_t)row * DIM + c8] = ll;
}

// ---------------- sq[n], e1[h][n], e2[h][n] ------------------------------------
__global__ __launch_bounds__(256) void sq_e_kernel(const float* __restrict__ BigC,
        const float* __restrict__ a, float* __restrict__ sq,
        float* __restrict__ e1, float* __restrict__ e2) {
    const int n = blockIdx.x;
    const int t = threadIdx.x;
    __shared__ float red[256];
    float xm = BigC[(size_t)n * BIGN + t];
    red[t] = xm * xm;
    __syncthreads();
    #pragma unroll
    for (int s = 128; s > 0; s >>= 1) { if (t < s) red[t] += red[t + s]; __syncthreads(); }
    if (t == 0) sq[n] = red[0];
    const int h = t >> 6, d = t & 63;
    float wh = BigC[(size_t)n * BIGN + 512 + t];
    float v1 = wh * a[h * 128 + d];
    float v2 = wh * a[h * 128 + 64 + d];
    #pragma unroll
    for (int s = 32; s > 0; s >>= 1) {
        v1 += __shfl_down(v1, s, 64);
        v2 += __shfl_down(v2, s, 64);
    }
    if (d == 0) { e1[h * NTOK + n] = v1; e2[h * NTOK + n] = v2; }
}

// ---------------- distance via bf16x3 MFMA + fused top-6 -----------------------
// Block: 256 thr (4 waves), tile 64i x 128j, K-chunks of 64, JCHUNK=256 (2 jt).
// LDS: Ah/Al [64][64] bf16, Bh/Bl [128][64] bf16 = 48KB, chunk-XOR swizzled
// (16B chunk c stored at c ^ (row&7)); staged via global_load_lds w/ pre-swizzled
// global source (linear LDS dest).  dot = hi*hi + hi*lo + lo*hi in fp32 MFMA.
__global__ __launch_bounds__(256) void dist_topk_kernel(
        const unsigned short* __restrict__ xmh, const unsigned short* __restrict__ xml,
        const float* __restrict__ sq, float* __restrict__ candD, int* __restrict__ candI) {
    __shared__ __align__(16) unsigned short sh[24576];   // 48KB
    unsigned short* Ah = sh;            // [64][64]
    unsigned short* Al = sh + 4096;
    unsigned short* Bh = sh + 8192;     // [128][64]
    unsigned short* Bl = sh + 16384;

    const int t = threadIdx.x;
    const int l = t & 63;
    const int w = t >> 6;               // wave 0..3
    const int wi = w >> 1;              // i-half (32 rows)
    const int wj = w & 1;               // j-half (64 cols)
    const int i0 = blockIdx.x * 64;
    const int jbase = blockIdx.y * JCHUNK;
    const int csrc = (l & 7) ^ ((l >> 3) & 7);   // pre-swizzled source chunk
    const int lrow8 = l >> 3;                    // row within 8-row slot

    float bd[KSEL]; int bi[KSEL];
    #pragma unroll
    for (int k = 0; k < KSEL; ++k) { bd[k] = 3.0e38f; bi[k] = 0x7fffffff; }

    for (int jt = 0; jt < JCHUNK / 128; ++jt) {
        const int j0 = jbase + jt * 128;
        f32x4 acc[2][4] = {};

        for (int kc = 0; kc < 4; ++kc) {
            __syncthreads();
            // ---- stage: A planes (2 slots/wave), B planes (4 slots/wave) ----
            #pragma unroll
            for (int q = 0; q < 2; ++q) {
                int r0 = (w * 2 + q) * 8;
                size_t goff = (size_t)(i0 + r0 + lrow8) * DIM + kc * 64 + csrc * 8;
                gload16(xmh + goff, &Ah[r0 * 64]);
                gload16(xml + goff, &Al[r0 * 64]);
            }
            #pragma unroll
            for (int q = 0; q < 4; ++q) {
                int r0 = (w * 4 + q) * 8;
                size_t goff = (size_t)(j0 + r0 + lrow8) * DIM + kc * 64 + csrc * 8;
                gload16(xmh + goff, &Bh[r0 * 64]);
                gload16(xml + goff, &Bl[r0 * 64]);
            }
            asm volatile("s_waitcnt vmcnt(0)" ::: "memory");
            __syncthreads();
            // ---- compute ----
            #pragma unroll
            for (int ksub = 0; ksub < 2; ++ksub) {
                const int cc = ((ksub * 4 + (l >> 4)) ^ (l & 7)) * 8;
                short8 ah[2], al[2], bh[4], bl[4];
                #pragma unroll
                for (int ti = 0; ti < 2; ++ti) {
                    int r = wi * 32 + ti * 16 + (l & 15);
                    ah[ti] = *(const short8*)&Ah[r * 64 + cc];
                    al[ti] = *(const short8*)&Al[r * 64 + cc];
                }
                #pragma unroll
                for (int tj = 0; tj < 4; ++tj) {
                    int r = wj * 64 + tj * 16 + (l & 15);
                    bh[tj] = *(const short8*)&Bh[r * 64 + cc];
                    bl[tj] = *(const short8*)&Bl[r * 64 + cc];
                }
                #pragma unroll
                for (int ti = 0; ti < 2; ++ti)
                    #pragma unroll
                    for (int tj = 0; tj < 4; ++tj) {
                        acc[ti][tj] = __builtin_amdgcn_mfma_f32_16x16x32_bf16(
                            ah[ti], bh[tj], acc[ti][tj], 0, 0, 0);
                        acc[ti][tj] = __builtin_amdgcn_mfma_f32_16x16x32_bf16(
                            ah[ti], bl[tj], acc[ti][tj], 0, 0, 0);
                        acc[ti][tj] = __builtin_amdgcn_mfma_f32_16x16x32_bf16(
                            al[ti], bh[tj], acc[ti][tj], 0, 0, 0);
                    }
            }
        }

        // ---- dump dot-products to LDS (overlay), keys scanned per-thread ----
        __syncthreads();
        float* Kd = (float*)sh;                         // [64][132]
        #pragma unroll
        for (int ti = 0; ti < 2; ++ti) {
            int ib = wi * 32 + ti * 16 + ((l >> 4) << 2);
            #pragma unroll
            for (int tj = 0; tj < 4; ++tj) {
                int jb = wj * 64 + tj * 16 + (l & 15);
                #pragma unroll
                for (int r = 0; r < 4; ++r)
                    Kd[(ib + r) * 132 + jb] = acc[ti][tj][r];
            }
        }
        __syncthreads();
        // scan: thread t -> row t>>2, 32-j slice (t&3)*32
        {
            const int il = t >> 2;
            const int jl0 = (t & 3) * 32;
            #pragma unroll
            for (int q4 = 0; q4 < 8; ++q4) {
                float4 dv = *(const float4*)&Kd[il * 132 + jl0 + q4 * 4];
                float4 sv = *(const float4*)&sq[j0 + jl0 + q4 * 4];
                #pragma unroll
                for (int r = 0; r < 4; ++r) {
                    float key = f4get(sv, r) - 2.0f * f4get(dv, r);
                    int   j   = j0 + jl0 + q4 * 4 + r;
                    INSERT6(bd, bi, key, j);
                }
            }
        }
    }

    // ---- block-level merge: 4 threads/row -> row top-6 -> candD/candI --------
    __syncthreads();
    float* MD = (float*)sh;                 // [64][24]
    int*   MI = (int*)sh + 64 * 24;
    {
        int base = (t >> 2) * 24 + (t & 3) * 6;
        #pragma unroll
        for (int k = 0; k < KSEL; ++k) { MD[base + k] = bd[k]; MI[base + k] = bi[k]; }
    }
    __syncthreads();
    if (t < 64) {
        size_t obase = ((size_t)(i0 + t) * JSPLIT + blockIdx.y) * KSEL;
        float lastD = -3.0e38f; int lastI = -1;
        #pragma unroll 1
        for (int k = 0; k < KSEL; ++k) {
            float bdv = 3.4e38f; int biv = 0x7fffffff;
            #pragma unroll 4
            for (int q = 0; q < 24; ++q) {
                float dv = MD[t * 24 + q]; int iv = MI[t * 24 + q];
                bool after  = (dv > lastD) || (dv == lastD && iv > lastI);
                bool better = (dv < bdv)  || (dv == bdv  && iv < biv);
                if (after && better) { bdv = dv; biv = iv; }
            }
            candD[obase + k] = bdv; candI[obase + k] = biv;
            lastD = bdv; lastI = biv;
        }
    }
}

// ---------------- merge per-range top-6 -> global top-6 (16 lanes/row) ---------
__global__ __launch_bounds__(256) void merge_kernel(const float* __restrict__ candD,
        const int* __restrict__ candI, int* __restrict__ idx6) {
    int gid = blockIdx.x * 256 + threadIdx.x;      // 65536 threads
    int row = gid >> 4;
    int lg  = gid & 15;                            // lane's JSPLIT range
    size_t base = ((size_t)row * JSPLIT + lg) * KSEL;
    float d[KSEL]; int ix[KSEL];
    #pragma unroll
    for (int k = 0; k < KSEL; ++k) { d[k] = candD[base + k]; ix[k] = candI[base + k]; }
    float lastD = -3.0e38f; int lastI = -1;
    #pragma unroll
    for (int k = 0; k < KSEL; ++k) {
        // lane-local best candidate strictly after (lastD,lastI) in lex order
        float bdv = 3.4e38f; int biv = 0x7fffffff;
        #pragma unroll
        for (int q = 0; q < KSEL; ++q) {
            bool after  = (d[q] > lastD) || (d[q] == lastD && ix[q] > lastI);
            bool better = (d[q] < bdv)  || (d[q] == bdv  && ix[q] < biv);
            if (after && better) { bdv = d[q]; biv = ix[q]; }
        }
        // cross-lane lex-min over the 16-lane group
        #pragma unroll
        for (int s = 1; s < 16; s <<= 1) {
            float od = __shfl_xor(bdv, s, 16);
            int   oi = __shfl_xor(biv, s, 16);
            if (od < bdv || (od == bdv && oi < biv)) { bdv = od; biv = oi; }
        }
        if (lg == 0) idx6[row * KSEL + k] = biv;
        lastD = bdv; lastI = biv;
    }
}

// ---------------- attention + residual + LN + ELU + out projection -------------
__global__ __launch_bounds__(256) void final_kernel(const float* __restrict__ BigC,
        const float* __restrict__ e1, const float* __restrict__ e2,
        const int* __restrict__ idx6, const float* __restrict__ ln_g,
        const float* __restrict__ ln_b, const float* __restrict__ Wo,
        const float* __restrict__ bo, float* __restrict__ out) {
    const int i = blockIdx.x;
    const int t = threadIdx.x;
    const int h = t >> 6;
    __shared__ int sidx[KSEL];
    __shared__ float red[256];
    if (t < KSEL) sidx[t] = idx6[i * KSEL + t];
    __syncthreads();
    const float e1i = e1[h * NTOK + i];
    float ev[KSEL];
    float m = -3.0e38f;
    #pragma unroll
    for (int k = 0; k < KSEL; ++k) {
        float v = e1i + e2[h * NTOK + sidx[k]];
        v = (v > 0.f) ? v : ALPHA_LR * v;
        ev[k] = v;
        m = fmaxf(m, v);
    }
    float ssum = 0.f;
    #pragma unroll
    for (int k = 0; k < KSEL; ++k) { ev[k] = expf(ev[k] - m); ssum += ev[k]; }
    float agg = 0.f;
    #pragma unroll
    for (int k = 0; k < KSEL; ++k)
        agg += ev[k] * BigC[(size_t)sidx[k] * BIGN + 512 + t];
    agg /= ssum;
    float hv = agg + BigC[(size_t)i * BIGN + 256 + t];
    // LayerNorm over 256
    red[t] = hv; __syncthreads();
    #pragma unroll
    for (int s = 128; s > 0; s >>= 1) { if (t < s) red[t] += red[t + s]; __syncthreads(); }
    float mu = red[0] * (1.f / 256.f);
    __syncthreads();
    float dv = hv - mu;
    red[t] = dv * dv; __syncthreads();
    #pragma unroll
    for (int s = 128; s > 0; s >>= 1) { if (t < s) red[t] += red[t + s]; __syncthreads(); }
    float var = red[0] * (1.f / 256.f);
    __syncthreads();
    float nv  = dv / sqrtf(var + LNEPS) * ln_g[t] + ln_b[t];
    float act = (nv > 0.f) ? nv : expm1f(nv);
    // out = act @ Wo + bo  (two 256-length dots)
    red[t] = act * Wo[t * 2 + 0]; __syncthreads();
    #pragma unroll
    for (int s = 128; s > 0; s >>= 1) { if (t < s) red[t] += red[t + s]; __syncthreads(); }
    float o0 = red[0];
    __syncthreads();
    red[t] = act * Wo[t * 2 + 1]; __syncthreads();
    #pragma unroll
    for (int s = 128; s > 0; s >>= 1) { if (t < s) red[t] += red[t + s]; __syncthreads(); }
    if (t == 0) { out[i * 2 + 0] = o0 + bo[0]; out[i * 2 + 1] = red[0] + bo[1]; }
}

extern "C" void kernel_launch(void* const* d_in, const int* in_sizes, int n_in,
                              void* d_out, int out_size, void* d_ws, size_t ws_size,
                              hipStream_t stream) {
    (void)in_sizes; (void)n_in; (void)out_size; (void)ws_size;
    const float* x    = (const float*)d_in[0];
    const float* Wm   = (const float*)d_in[1];
    const float* bm   = (const float*)d_in[2];
    const float* W    = (const float*)d_in[3];
    const float* a    = (const float*)d_in[4];
    const float* Wr   = (const float*)d_in[5];
    const float* br   = (const float*)d_in[6];
    const float* ln_g = (const float*)d_in[7];
    const float* ln_b = (const float*)d_in[8];
    const float* Wo   = (const float*)d_in[9];
    const float* bo   = (const float*)d_in[10];
    float* out = (float*)d_out;

    char* ws = (char*)d_ws;
    float*          BigB    = (float*)(ws + 0);              // 786432 B
    float*          BigBias = (float*)(ws + 786432);         // -> 789504
    float*          BigC    = (float*)(ws + 789504);         // -> 13372416
    float*          sq      = (float*)(ws + 13372416);       // -> 13388800
    float*          e1      = (float*)(ws + 13388800);       // -> 13454336
    float*          e2      = (float*)(ws + 13454336);       // -> 13519872
    unsigned short* xmh     = (unsigned short*)(ws + 13519872); // -> 15617024
    unsigned short* xml     = (unsigned short*)(ws + 15617024); // -> 17714176
    float*          candD   = (float*)(ws + 17714176);       // 4096*16*6*4 -> 19287040
    int*            candI   = (int*)  (ws + 19287040);       // -> 20859904
    int*            idx6    = (int*)  (ws + 20859904);       // -> 20958208

    hipLaunchKernelGGL(repack_kernel, dim3(768), dim3(256), 0, stream,
                       Wm, bm, W, Wr, br, BigB, BigBias);
    hipLaunchKernelGGL(gemm_kernel, dim3(64, 12), dim3(256), 0, stream,
                       x, BigB, BigBias, BigC);
    hipLaunchKernelGGL(convert_kernel, dim3(512), dim3(256), 0, stream,
                       BigC, xmh, xml);
    hipLaunchKernelGGL(sq_e_kernel, dim3(4096), dim3(256), 0, stream,
                       BigC, a, sq, e1, e2);
    hipLaunchKernelGGL(dist_topk_kernel, dim3(64, JSPLIT), dim3(256), 0, stream,
                       xmh, xml, sq, candD, candI);
    hipLaunchKernelGGL(merge_kernel, dim3(256), dim3(256), 0, stream,
                       candD, candI, idx6);
    hipLaunchKernelGGL(final_kernel, dim3(4096), dim3(256), 0, stream,
                       BigC, e1, e2, idx6, ln_g, ln_b, Wo, bo, out);
}